// Round 1
// baseline (117.417 us; speedup 1.0000x reference)
//
#include <hip/hip_runtime.h>

// Gaussian 3x3 conv forward, B=64, C=1, H=W=512, N_MULT=1.
// taps = max(rint(clamp(w,0.001,0.999)*clamp(wf,1.001,254.999)), 0.001), then
// 3x3 conv, zero padding=1. Output [1,64,1,512,512] fp32 (flat layout == input).
//
// v2 changes vs. 110.5us baseline:
//  - RR 8 -> 16: halo read redundancy 1.25x -> 1.125x, half the wave-edge fixups.
//  - Rolling accumulator: out row (j-2) is finalized as soon as input row j is
//    consumed and is nontemporal-stored immediately. Only ~3 float4 accs are
//    live at any point (vs 8..16), cutting VGPRs and letting the compiler
//    software-pipeline the 18 independent row loads deeply.
//  - XCD-contiguous swizzle: grid=1024 = 8 XCDs x 128 blocks; (bid&7)*128+(bid>>3)
//    gives each XCD 8 whole batches so strip-boundary halo rows re-read from the
//    SAME XCD's L2 rather than a foreign one.

#define BB 64
#define HH 512
#define WW 512
#define W4 (WW / 4)          // 128 float4 per row
#define RR 16                // output rows per thread
#define NSTRIP (HH / RR)     // 32 strips
#define NTHREADS (BB * NSTRIP * W4)   // 262,144
#define GRID (NTHREADS / 256)         // 1024 (8-divisible -> bijective XCD swizzle)

typedef float vfloat4 __attribute__((ext_vector_type(4)));  // for nontemporal builtin

__global__ __launch_bounds__(256) void gauss3x3_kernel(
    const float* __restrict__ in,     // [B,1,H,W]
    const float* __restrict__ wgt,    // [1,9]
    const float* __restrict__ wfac,   // [1,1]
    float* __restrict__ out)          // [1,B,1,H,W]
{
    // Derive the 9 taps (redundant per thread; scalar broadcast loads).
    float wf = fminf(fmaxf(wfac[0], 1.001f), 254.999f);
    float k[9];
#pragma unroll
    for (int i = 0; i < 9; ++i) {
        float wc = fminf(fmaxf(wgt[i], 0.001f), 0.999f);
        k[i] = fmaxf(rintf(wc * wf), 0.001f);   // rintf = round-half-even = jnp.round
    }

    // XCD-contiguous block swizzle (bijective: 1024 = 8 * 128).
    const int bid = blockIdx.x;
    const int swz = (bid & 7) * (GRID / 8) + (bid >> 3);
    const int tid = swz * 256 + (int)threadIdx.x;

    const int lane  = threadIdx.x & 63;
    const int x4    = tid & (W4 - 1);            // lane-varying: column (float4)
    const int strip = (tid >> 7) & (NSTRIP - 1); // wave-uniform: 16-row strip
    const int b     = tid >> 12;                 // wave-uniform: batch
    if (b >= BB) return;

    const int y0 = strip * RR;
    const int x0 = x4 * 4;
    const float* img  = in  + (size_t)b * HH * WW;
    float*       outp = out + (size_t)b * HH * WW;

    float4 acc[RR];   // fully unrolled below => compile-time indices; live range
                      // of acc[i] is only iterations j=i..i+2 (regalloc reuses).

    // Input rows j=0..RR+1 map to ry = y0-1+j. Input row j contributes to:
    //   out i=j   with tap row 0 (k[0..2], dy=-1)  -> initializes acc[j]
    //   out i=j-1 with tap row 1 (k[3..5], dy= 0)
    //   out i=j-2 with tap row 2 (k[6..8], dy=+1)  -> finalizes acc[j-2], store it
#pragma unroll
    for (int j = 0; j < RR + 2; ++j) {
        const int ry = y0 - 1 + j;
        float4 c = make_float4(0.f, 0.f, 0.f, 0.f);
        float  l = 0.f, r = 0.f;
        if (ry >= 0 && ry < HH) {                  // wave-uniform branch
            const float* row = img + (size_t)ry * WW;
            c = *(const float4*)(row + x0);        // aligned 16B load
            l = __shfl_up(c.w, 1);                 // lane-1's last element
            r = __shfl_down(c.x, 1);               // lane+1's first element
            if (lane == 0)                         // wave-edge fix-up (1 active lane)
                l = (x0 > 0) ? row[x0 - 1] : 0.f;
            if (lane == 63)
                r = (x0 + 4 < WW) ? row[x0 + 4] : 0.f;
        }

        if (j < RR) {                              // t=0: fresh init of acc[j]
            acc[j].x = k[0] * l   + k[1] * c.x + k[2] * c.y;
            acc[j].y = k[0] * c.x + k[1] * c.y + k[2] * c.z;
            acc[j].z = k[0] * c.y + k[1] * c.z + k[2] * c.w;
            acc[j].w = k[0] * c.z + k[1] * c.w + k[2] * r;
        }
        if (j >= 1 && (j - 1) < RR) {              // t=1: accumulate into acc[j-1]
            const int i = j - 1;
            acc[i].x = fmaf(k[3], l,   fmaf(k[4], c.x, fmaf(k[5], c.y, acc[i].x)));
            acc[i].y = fmaf(k[3], c.x, fmaf(k[4], c.y, fmaf(k[5], c.z, acc[i].y)));
            acc[i].z = fmaf(k[3], c.y, fmaf(k[4], c.z, fmaf(k[5], c.w, acc[i].z)));
            acc[i].w = fmaf(k[3], c.z, fmaf(k[4], c.w, fmaf(k[5], r,   acc[i].w)));
        }
        if (j >= 2) {                              // t=2: finalize acc[j-2] + store
            const int i = j - 2;
            acc[i].x = fmaf(k[6], l,   fmaf(k[7], c.x, fmaf(k[8], c.y, acc[i].x)));
            acc[i].y = fmaf(k[6], c.x, fmaf(k[7], c.y, fmaf(k[8], c.z, acc[i].y)));
            acc[i].z = fmaf(k[6], c.y, fmaf(k[7], c.z, fmaf(k[8], c.w, acc[i].z)));
            acc[i].w = fmaf(k[6], c.z, fmaf(k[7], c.w, fmaf(k[8], r,   acc[i].w)));
            vfloat4* dst = (vfloat4*)(outp + (size_t)(y0 + i) * WW + x0);
            vfloat4 v = { acc[i].x, acc[i].y, acc[i].z, acc[i].w };
            __builtin_nontemporal_store(v, dst);   // streamed; output has no reuse
        }
    }
}

extern "C" void kernel_launch(void* const* d_in, const int* in_sizes, int n_in,
                              void* d_out, int out_size, void* d_ws, size_t ws_size,
                              hipStream_t stream) {
    const float* in   = (const float*)d_in[0];   // [64,1,512,512]
    const float* wgt  = (const float*)d_in[1];   // [1,9]
    const float* wfac = (const float*)d_in[2];   // [1,1]
    float* out = (float*)d_out;                  // [1,64,1,512,512]

    gauss3x3_kernel<<<GRID, 256, 0, stream>>>(in, wgt, wfac, out);
}

// Round 2
// 114.526 us; speedup vs baseline: 1.0252x; 1.0252x over previous
//
#include <hip/hip_runtime.h>

// Gaussian 3x3 conv forward, B=64, C=1, H=W=512, N_MULT=1.
// taps = max(rint(clamp(w,0.001,0.999)*clamp(wf,1.001,254.999)), 0.001), then
// 3x3 conv, zero padding=1. Output [1,64,1,512,512] fp32 (flat layout == input).
//
// v3: RR back to 8 (v2's RR=16 halved occupancy 32->16 waves/CU and cost +22%
// kernel time; full TLP matters more than halo-read savings since the 67 MB
// input is L3-resident). Kept from v2: rolling accumulator + immediate NT store
// (only ~3 float4 accs live -> low VGPR), XCD-contiguous block swizzle.
// New: the two wave-edge fix-up loads (lane 0 left halo, lane 63 right halo)
// are merged into ONE exec-masked load with 2 active lanes -- 10 fewer VMEM
// instructions per wave.

#define BB 64
#define HH 512
#define WW 512
#define W4 (WW / 4)          // 128 float4 per row
#define RR 8                 // output rows per thread
#define NSTRIP (HH / RR)     // 64 strips
#define NTHREADS (BB * NSTRIP * W4)   // 524,288
#define GRID (NTHREADS / 256)         // 2048 (8-divisible -> bijective XCD swizzle)

typedef float vfloat4 __attribute__((ext_vector_type(4)));  // for nontemporal builtin

__global__ __launch_bounds__(256) void gauss3x3_kernel(
    const float* __restrict__ in,     // [B,1,H,W]
    const float* __restrict__ wgt,    // [1,9]
    const float* __restrict__ wfac,   // [1,1]
    float* __restrict__ out)          // [1,B,1,H,W]
{
    // Derive the 9 taps (redundant per thread; scalar broadcast loads).
    float wf = fminf(fmaxf(wfac[0], 1.001f), 254.999f);
    float k[9];
#pragma unroll
    for (int i = 0; i < 9; ++i) {
        float wc = fminf(fmaxf(wgt[i], 0.001f), 0.999f);
        k[i] = fmaxf(rintf(wc * wf), 0.001f);   // rintf = round-half-even = jnp.round
    }

    // XCD-contiguous block swizzle (bijective: 2048 = 8 * 256). Neighboring
    // strips (which share halo rows) stay on the same XCD's L2.
    const int bid = blockIdx.x;
    const int swz = (bid & 7) * (GRID / 8) + (bid >> 3);
    const int tid = swz * 256 + (int)threadIdx.x;

    const int lane  = threadIdx.x & 63;
    const int x4    = tid & (W4 - 1);            // lane-varying: column (float4)
    const int strip = (tid >> 7) & (NSTRIP - 1); // wave-uniform: 8-row strip
    const int b     = tid >> 13;                 // wave-uniform: batch
    if (b >= BB) return;

    const int y0 = strip * RR;
    const int x0 = x4 * 4;
    const float* img  = in  + (size_t)b * HH * WW;
    float*       outp = out + (size_t)b * HH * WW;

    float4 acc[RR];   // fully unrolled => compile-time indices; live range of
                      // acc[i] is only iterations j=i..i+2 (regalloc reuses).

    // Input rows j=0..RR+1 map to ry = y0-1+j. Input row j contributes to:
    //   out i=j   with tap row 0 (k[0..2], dy=-1)  -> initializes acc[j]
    //   out i=j-1 with tap row 1 (k[3..5], dy= 0)
    //   out i=j-2 with tap row 2 (k[6..8], dy=+1)  -> finalizes acc[j-2], store it
#pragma unroll
    for (int j = 0; j < RR + 2; ++j) {
        const int ry = y0 - 1 + j;
        float4 c = make_float4(0.f, 0.f, 0.f, 0.f);
        float  l = 0.f, r = 0.f;
        if (ry >= 0 && ry < HH) {                  // wave-uniform branch
            const float* row = img + (size_t)ry * WW;
            c = *(const float4*)(row + x0);        // aligned 16B load
            l = __shfl_up(c.w, 1);                 // lane-1's last element
            r = __shfl_down(c.x, 1);               // lane+1's first element
            const bool e0  = (lane == 0);
            const bool e63 = (lane == 63);
            if (e0 | e63) {                        // ONE load, 2 active lanes
                const int xo = x0 + (e0 ? -1 : 4); // lane0: left halo, lane63: right
                const float ev = (xo >= 0 && xo < WW) ? row[xo] : 0.f;
                if (e0) l = ev; else r = ev;       // cndmask under exec mask
            }
        }

        if (j < RR) {                              // t=0: fresh init of acc[j]
            acc[j].x = k[0] * l   + k[1] * c.x + k[2] * c.y;
            acc[j].y = k[0] * c.x + k[1] * c.y + k[2] * c.z;
            acc[j].z = k[0] * c.y + k[1] * c.z + k[2] * c.w;
            acc[j].w = k[0] * c.z + k[1] * c.w + k[2] * r;
        }
        if (j >= 1 && (j - 1) < RR) {              // t=1: accumulate into acc[j-1]
            const int i = j - 1;
            acc[i].x = fmaf(k[3], l,   fmaf(k[4], c.x, fmaf(k[5], c.y, acc[i].x)));
            acc[i].y = fmaf(k[3], c.x, fmaf(k[4], c.y, fmaf(k[5], c.z, acc[i].y)));
            acc[i].z = fmaf(k[3], c.y, fmaf(k[4], c.z, fmaf(k[5], c.w, acc[i].z)));
            acc[i].w = fmaf(k[3], c.z, fmaf(k[4], c.w, fmaf(k[5], r,   acc[i].w)));
        }
        if (j >= 2) {                              // t=2: finalize acc[j-2] + store
            const int i = j - 2;
            acc[i].x = fmaf(k[6], l,   fmaf(k[7], c.x, fmaf(k[8], c.y, acc[i].x)));
            acc[i].y = fmaf(k[6], c.x, fmaf(k[7], c.y, fmaf(k[8], c.z, acc[i].y)));
            acc[i].z = fmaf(k[6], c.y, fmaf(k[7], c.z, fmaf(k[8], c.w, acc[i].z)));
            acc[i].w = fmaf(k[6], c.z, fmaf(k[7], c.w, fmaf(k[8], r,   acc[i].w)));
            vfloat4* dst = (vfloat4*)(outp + (size_t)(y0 + i) * WW + x0);
            vfloat4 v = { acc[i].x, acc[i].y, acc[i].z, acc[i].w };
            __builtin_nontemporal_store(v, dst);   // streamed; output has no reuse
        }
    }
}

extern "C" void kernel_launch(void* const* d_in, const int* in_sizes, int n_in,
                              void* d_out, int out_size, void* d_ws, size_t ws_size,
                              hipStream_t stream) {
    const float* in   = (const float*)d_in[0];   // [64,1,512,512]
    const float* wgt  = (const float*)d_in[1];   // [1,9]
    const float* wfac = (const float*)d_in[2];   // [1,1]
    float* out = (float*)d_out;                  // [1,64,1,512,512]

    gauss3x3_kernel<<<GRID, 256, 0, stream>>>(in, wgt, wfac, out);
}